// Round 15
// baseline (569.627 us; speedup 1.0000x reference)
//
#include <hip/hip_runtime.h>
#include <hip/hip_cooperative_groups.h>

namespace cg = cooperative_groups;

// Coords are all {0,1}; STRIDES is a mixed-radix positional encoding, so each
// row maps bijectively to a 16-bit pattern. Whole op = 65536-bin float
// histogram + gather.
//
// R0-R2: global fp32 atomicAdd executes at the memory-side coherence point
// regardless of scope -> no global atomics anywhere.
// R4: LDS-partitioned build (8 parts x 8192-bin 32KB LDS hists).
// R6: 4-lane __shfl_xor nibble combine (coalesced 16B/lane reads).
// R10-R13 lesson: extract micro-structure (scalar/vector/shuffle/MLP8/nt/DMA)
// does NOT move end-to-end time; streams already run ~6 TB/s timed. The
// remaining ~15us gap vs work-sum is inter-kernel launch/tail overhead.
// R14: single cooperative kernel, grid.sync() between phases. 512x512,
// launch_bounds(512,4) -> <=128 VGPR -> 2 blocks/CU co-resident.

#define REL_W 16
#define NBINS 65536
#define NPART 8
#define BPP 8192        // bins per partition (32 KB as floats)
#define NSLICES 64
#define BUILD_BLK 1024
#define BLK 256
#define EUNROLL 8
#define CBLK 512
#define CGRID (NPART * NSLICES)   // 512

typedef unsigned short ushort8_t __attribute__((ext_vector_type(8)));
typedef int   int4v   __attribute__((ext_vector_type(4)));

__device__ __forceinline__ unsigned pattern_of(const int* __restrict__ row) {
    const int4* p = reinterpret_cast<const int4*>(row);
    unsigned pat = 0;
#pragma unroll
    for (int k = 0; k < 4; ++k) {
        int4 v = p[k];
        pat |= (unsigned)(v.x & 1) << (k * 4 + 0);
        pat |= (unsigned)(v.y & 1) << (k * 4 + 1);
        pat |= (unsigned)(v.z & 1) << (k * 4 + 2);
        pat |= (unsigned)(v.w & 1) << (k * 4 + 3);
    }
    return pat;
}

__device__ __forceinline__ unsigned nibble_of(int4v v) {
    return (unsigned)(v.x & 1) | ((unsigned)(v.y & 1) << 1) |
           ((unsigned)(v.z & 1) << 2) | ((unsigned)(v.w & 1) << 3);
}

// ===================== fused cooperative kernel =====================
__global__ __launch_bounds__(CBLK, 4) void fused_all(
    const int* __restrict__ stored, const int* __restrict__ queries,
    const float* __restrict__ vals, float* __restrict__ out,
    unsigned short* __restrict__ pat_s, unsigned short* __restrict__ pat_q,
    float* __restrict__ part_hists, float* __restrict__ final_h,
    int ns, int nq)
{
    cg::grid_group grid = cg::this_grid();
    __shared__ float lh[BPP];
    const int b = blockIdx.x;
    const int tid = threadIdx.x;
    const long ns4 = (long)ns * 4;
    const long tot4 = (long)(ns + nq) * 4;
    const long chunk = (((tot4 + CGRID - 1) / CGRID) + 3) & ~3L;  // %4 == 0
    const unsigned k = (unsigned)tid & 3, sh = 4 * k;

    // ---- phase 1: extract both coord arrays -> u16 patterns ----
    {
        const int4v* sv = reinterpret_cast<const int4v*>(stored);
        const int4v* qv = reinterpret_cast<const int4v*>(queries);
        long lo = (long)b * chunk;
        long hi = lo + chunk; if (hi > tot4) hi = tot4;
        if (lo < hi) {
            if (hi <= ns4) {                       // pure stored chunk
                const int4v* __restrict__ src = sv + lo;
                unsigned short* __restrict__ dst = pat_s + (lo >> 2);
                int m = (int)(hi - lo);
#pragma unroll 4
                for (int i = tid; i < m; i += CBLK) {
                    unsigned val = nibble_of(src[i]) << sh;
                    val |= __shfl_xor(val, 1);
                    val |= __shfl_xor(val, 2);
                    if (k == 0) dst[i >> 2] = (unsigned short)val;
                }
            } else if (lo >= ns4) {                // pure query chunk
                const int4v* __restrict__ src = qv + (lo - ns4);
                unsigned short* __restrict__ dst = pat_q + ((lo - ns4) >> 2);
                int m = (int)(hi - lo);
#pragma unroll 4
                for (int i = tid; i < m; i += CBLK) {
                    unsigned val = nibble_of(src[i]) << sh;
                    val |= __shfl_xor(val, 1);
                    val |= __shfl_xor(val, 2);
                    if (k == 0) dst[i >> 2] = (unsigned short)val;
                }
            } else {                               // straddles (not hit at our sizes)
                for (long g = lo + tid; g < hi; g += CBLK) {
                    int4v v = (g < ns4) ? sv[g] : qv[g - ns4];
                    unsigned val = nibble_of(v) << sh;
                    val |= __shfl_xor(val, 1);
                    val |= __shfl_xor(val, 2);
                    if (k == 0) {
                        if (g < ns4) pat_s[g >> 2] = (unsigned short)val;
                        else         pat_q[(g - ns4) >> 2] = (unsigned short)val;
                    }
                }
            }
        }
    }
    __threadfence();
    grid.sync();

    // ---- phase 2: LDS-partitioned histogram build ----
    {
        unsigned part  = (unsigned)b / NSLICES;
        unsigned slice = (unsigned)b % NSLICES;
        for (int i = tid; i < BPP; i += CBLK) lh[i] = 0.0f;
        __syncthreads();
        int per = ((ns + NSLICES - 1) / NSLICES + 7) & ~7;
        int lo = (int)slice * per;
        int hi = min(ns, lo + per);
        if (lo < hi) {
            int m = hi - lo;
            int nvec = m >> 3;
            const ushort8_t* pv = reinterpret_cast<const ushort8_t*>(pat_s + lo);
            const float4*    vv = reinterpret_cast<const float4*>(vals + lo);
            for (int v = tid; v < nvec; v += CBLK) {
                ushort8_t p8 = pv[v];
                float4 v0 = vv[2 * v];
                float4 v1 = vv[2 * v + 1];
                float vsc[8] = {v0.x, v0.y, v0.z, v0.w, v1.x, v1.y, v1.z, v1.w};
#pragma unroll
                for (int kk = 0; kk < 8; ++kk) {
                    unsigned pat = p8[kk];
                    if ((pat >> 13) == part)
                        atomicAdd(&lh[pat & (BPP - 1)], vsc[kk]);   // ds_add_f32
                }
            }
            for (int i = lo + (nvec << 3) + tid; i < hi; i += CBLK) {
                unsigned pat = pat_s[i];
                if ((pat >> 13) == part)
                    atomicAdd(&lh[pat & (BPP - 1)], vals[i]);
            }
        }
        __syncthreads();
        float* dst = part_hists + (size_t)b * BPP;
        for (int i = tid; i < BPP; i += CBLK) dst[i] = lh[i];
    }
    __threadfence();
    grid.sync();

    // ---- phase 3: reduce 64 slice-copies -> final hist (first 128 blocks) ----
    {
        int g = b * CBLK + tid;
        if (g < NBINS) {
            unsigned part = (unsigned)g >> 13;
            unsigned idx  = (unsigned)g & (BPP - 1);
            const float* src = part_hists + ((size_t)part * NSLICES) * BPP + idx;
            float s = 0.0f;
#pragma unroll 8
            for (int sl = 0; sl < NSLICES; ++sl) s += src[(size_t)sl * BPP];
            final_h[g] = s;
        }
    }
    __threadfence();
    grid.sync();

    // ---- phase 4: gather (8 queries per thread) ----
    {
        int t = b * CBLK + tid;
        int base = t * 8;
        if (base + 8 <= nq) {
            ushort4 a = *reinterpret_cast<const ushort4*>(pat_q + base);
            ushort4 c = *reinterpret_cast<const ushort4*>(pat_q + base + 4);
            float4 o0, o1;
            o0.x = final_h[a.x]; o0.y = final_h[a.y]; o0.z = final_h[a.z]; o0.w = final_h[a.w];
            o1.x = final_h[c.x]; o1.y = final_h[c.y]; o1.z = final_h[c.z]; o1.w = final_h[c.w];
            *reinterpret_cast<float4*>(out + base)     = o0;
            *reinterpret_cast<float4*>(out + base + 4) = o1;
        } else {
            for (int i = base; i < nq; ++i) out[i] = final_h[pat_q[i]];
        }
    }
}

// ===================== fallback 4-kernel path (R10 structure) =====================
__device__ __forceinline__ void emit_pat(unsigned g, unsigned nib, unsigned k, unsigned sh,
                                         unsigned short* __restrict__ dst) {
    unsigned val = nib << sh;
    val |= __shfl_xor(val, 1);
    val |= __shfl_xor(val, 2);
    if (k == 0) dst[g >> 2] = (unsigned short)val;
}

__global__ __launch_bounds__(BLK) void extract_both8(const int* __restrict__ stored,
                                                     const int* __restrict__ queries,
                                                     unsigned short* __restrict__ pat_s,
                                                     unsigned short* __restrict__ pat_q,
                                                     int ns, int nq) {
    const int4v* sv = reinterpret_cast<const int4v*>(stored);
    const int4v* qv = reinterpret_cast<const int4v*>(queries);
    int ns4  = ns * 4;
    int tot4 = (ns + nq) * 4;
    int blk_lo = blockIdx.x * (BLK * EUNROLL);
    int blk_hi = blk_lo + BLK * EUNROLL;
    int base   = blk_lo + (int)threadIdx.x;
    unsigned k  = (unsigned)threadIdx.x & 3;
    unsigned sh = 4 * k;

    if (blk_hi <= ns4) {
        int4v v0 = sv[base + 0 * BLK], v1 = sv[base + 1 * BLK];
        int4v v2 = sv[base + 2 * BLK], v3 = sv[base + 3 * BLK];
        int4v v4 = sv[base + 4 * BLK], v5 = sv[base + 5 * BLK];
        int4v v6 = sv[base + 6 * BLK], v7 = sv[base + 7 * BLK];
        emit_pat(base + 0 * BLK, nibble_of(v0), k, sh, pat_s);
        emit_pat(base + 1 * BLK, nibble_of(v1), k, sh, pat_s);
        emit_pat(base + 2 * BLK, nibble_of(v2), k, sh, pat_s);
        emit_pat(base + 3 * BLK, nibble_of(v3), k, sh, pat_s);
        emit_pat(base + 4 * BLK, nibble_of(v4), k, sh, pat_s);
        emit_pat(base + 5 * BLK, nibble_of(v5), k, sh, pat_s);
        emit_pat(base + 6 * BLK, nibble_of(v6), k, sh, pat_s);
        emit_pat(base + 7 * BLK, nibble_of(v7), k, sh, pat_s);
    } else if (blk_lo >= ns4 && blk_hi <= tot4) {
        int b = base - ns4;
        int4v v0 = qv[b + 0 * BLK], v1 = qv[b + 1 * BLK];
        int4v v2 = qv[b + 2 * BLK], v3 = qv[b + 3 * BLK];
        int4v v4 = qv[b + 4 * BLK], v5 = qv[b + 5 * BLK];
        int4v v6 = qv[b + 6 * BLK], v7 = qv[b + 7 * BLK];
        emit_pat(b + 0 * BLK, nibble_of(v0), k, sh, pat_q);
        emit_pat(b + 1 * BLK, nibble_of(v1), k, sh, pat_q);
        emit_pat(b + 2 * BLK, nibble_of(v2), k, sh, pat_q);
        emit_pat(b + 3 * BLK, nibble_of(v3), k, sh, pat_q);
        emit_pat(b + 4 * BLK, nibble_of(v4), k, sh, pat_q);
        emit_pat(b + 5 * BLK, nibble_of(v5), k, sh, pat_q);
        emit_pat(b + 6 * BLK, nibble_of(v6), k, sh, pat_q);
        emit_pat(b + 7 * BLK, nibble_of(v7), k, sh, pat_q);
    } else {
#pragma unroll
        for (int j = 0; j < EUNROLL; ++j) {
            int g = base + j * BLK;
            if (g < tot4) {
                int4v v = (g < ns4) ? sv[g] : qv[g - ns4];
                unsigned val = nibble_of(v) << sh;
                val |= __shfl_xor(val, 1);
                val |= __shfl_xor(val, 2);
                if (k == 0) {
                    if (g < ns4) pat_s[g >> 2] = (unsigned short)val;
                    else         pat_q[(g - ns4) >> 2] = (unsigned short)val;
                }
            }
        }
    }
}

__global__ __launch_bounds__(BUILD_BLK) void build_parts(const unsigned short* __restrict__ pats,
                                                         const float* __restrict__ vals,
                                                         float* __restrict__ part_hists, int n) {
    __shared__ float lh[BPP];
    unsigned part  = blockIdx.x / NSLICES;
    unsigned slice = blockIdx.x % NSLICES;
    for (int b = threadIdx.x; b < BPP; b += BUILD_BLK) lh[b] = 0.0f;
    __syncthreads();
    int per = ((n + NSLICES - 1) / NSLICES + 7) & ~7;
    int lo = (int)slice * per;
    int hi = min(n, lo + per);
    if (lo < hi) {
        int m = hi - lo;
        int nvec = m >> 3;
        const ushort8_t* pv = reinterpret_cast<const ushort8_t*>(pats + lo);
        const float4*    vv = reinterpret_cast<const float4*>(vals + lo);
        for (int v = threadIdx.x; v < nvec; v += BUILD_BLK) {
            ushort8_t p8 = pv[v];
            float4 v0 = vv[2 * v];
            float4 v1 = vv[2 * v + 1];
            float vsc[8] = {v0.x, v0.y, v0.z, v0.w, v1.x, v1.y, v1.z, v1.w};
#pragma unroll
            for (int kk = 0; kk < 8; ++kk) {
                unsigned pat = p8[kk];
                if ((pat >> 13) == part)
                    atomicAdd(&lh[pat & (BPP - 1)], vsc[kk]);
            }
        }
        for (int i = lo + (nvec << 3) + (int)threadIdx.x; i < hi; i += BUILD_BLK) {
            unsigned pat = pats[i];
            if ((pat >> 13) == part)
                atomicAdd(&lh[pat & (BPP - 1)], vals[i]);
        }
    }
    __syncthreads();
    float* dst = part_hists + (size_t)blockIdx.x * BPP;
    for (int b = threadIdx.x; b < BPP; b += BUILD_BLK) dst[b] = lh[b];
}

__global__ void reduce_parts(const float* __restrict__ part_hists, float* __restrict__ final_h) {
    int g = blockIdx.x * blockDim.x + threadIdx.x;
    unsigned part = (unsigned)g >> 13;
    unsigned b = (unsigned)g & (BPP - 1);
    const float* src = part_hists + ((size_t)part * NSLICES) * BPP + b;
    float s = 0.0f;
#pragma unroll 8
    for (int sl = 0; sl < NSLICES; ++sl) s += src[(size_t)sl * BPP];
    final_h[g] = s;
}

__global__ __launch_bounds__(BLK) void gather_pat(const unsigned short* __restrict__ pq,
                                                  const float* __restrict__ h,
                                                  float* __restrict__ out, int n) {
    int t = blockIdx.x * blockDim.x + threadIdx.x;
    int base = t * 4;
    if (base + 4 <= n) {
        ushort4 p4 = *reinterpret_cast<const ushort4*>(pq + base);
        float4 o;
        o.x = h[p4.x]; o.y = h[p4.y]; o.z = h[p4.z]; o.w = h[p4.w];
        *reinterpret_cast<float4*>(out + base) = o;
    } else {
        for (int i = base; i < n; ++i) out[i] = h[pq[i]];
    }
}

// ---- tiny-ws fallback (R0 path) ----
__global__ void build_hist_dev(const int* __restrict__ coords, const float* __restrict__ vals,
                               float* __restrict__ hist, int n) {
    int i = blockIdx.x * blockDim.x + threadIdx.x;
    if (i >= n) return;
    atomicAdd(&hist[pattern_of(coords + (size_t)i * REL_W)], vals[i]);
}
__global__ void gather_coord(const int* __restrict__ queries, const float* __restrict__ hist,
                             float* __restrict__ out, int n) {
    int i = blockIdx.x * blockDim.x + threadIdx.x;
    if (i >= n) return;
    out[i] = hist[pattern_of(queries + (size_t)i * REL_W)];
}

static inline size_t align_up(size_t x, size_t a) { return (x + a - 1) & ~(a - 1); }

extern "C" void kernel_launch(void* const* d_in, const int* in_sizes, int n_in,
                              void* d_out, int out_size, void* d_ws, size_t ws_size,
                              hipStream_t stream) {
    const int*   stored  = (const int*)d_in[0];   // [N_store, 16] int32
    const int*   queries = (const int*)d_in[1];   // [N_query, 16] int32
    const float* vals    = (const float*)d_in[2]; // [N_store] f32
    float*       out     = (float*)d_out;         // [N_query] f32

    int n_store = in_sizes[0] / REL_W;
    int n_query = in_sizes[1] / REL_W;

    // workspace layout
    size_t off_pat_s = 0;
    size_t off_pat_q = align_up(off_pat_s + (size_t)n_store * 2, 256);
    size_t off_hists = align_up(off_pat_q + (size_t)n_query * 2, 256);
    size_t off_final = off_hists + (size_t)NPART * NSLICES * BPP * sizeof(float);
    size_t need      = off_final + (size_t)NBINS * sizeof(float);

    if (ws_size >= need) {
        unsigned short* pat_s = (unsigned short*)((char*)d_ws + off_pat_s);
        unsigned short* pat_q = (unsigned short*)((char*)d_ws + off_pat_q);
        float* part_hists     = (float*)((char*)d_ws + off_hists);
        float* final_h        = (float*)((char*)d_ws + off_final);

        void* args[10] = {(void*)&stored, (void*)&queries, (void*)&vals, (void*)&out,
                          (void*)&pat_s, (void*)&pat_q, (void*)&part_hists, (void*)&final_h,
                          (void*)&n_store, (void*)&n_query};
        hipError_t e = hipLaunchCooperativeKernel(reinterpret_cast<void*>(fused_all),
                                                  dim3(CGRID), dim3(CBLK), args, 0, stream);
        if (e != hipSuccess) {
            // fallback: proven 4-kernel path
            int tot4    = (n_store + n_query) * 4;
            int eblocks = (tot4 + BLK * EUNROLL - 1) / (BLK * EUNROLL);
            int gblocks = (n_query + BLK * 4 - 1) / (BLK * 4);
            extract_both8<<<eblocks, BLK, 0, stream>>>(stored, queries, pat_s, pat_q, n_store, n_query);
            build_parts<<<NPART * NSLICES, BUILD_BLK, 0, stream>>>(pat_s, vals, part_hists, n_store);
            reduce_parts<<<NBINS / BLK, BLK, 0, stream>>>(part_hists, final_h);
            gather_pat<<<gblocks, BLK, 0, stream>>>(pat_q, final_h, out, n_query);
        }
    } else {
        float* hist = (float*)d_ws;
        hipMemsetAsync(d_ws, 0, NBINS * sizeof(float), stream);
        build_hist_dev<<<(n_store + BLK - 1) / BLK, BLK, 0, stream>>>(stored, vals, hist, n_store);
        gather_coord<<<(n_query + BLK - 1) / BLK, BLK, 0, stream>>>(queries, hist, out, n_query);
    }
}

// Round 16
// 76.678 us; speedup vs baseline: 7.4288x; 7.4288x over previous
//
#include <hip/hip_runtime.h>

// Coords are all {0,1}; STRIDES is a mixed-radix positional encoding, so each
// row maps bijectively to a 16-bit pattern. Whole op = 65536-bin float
// histogram + gather.
//
// FINAL STRUCTURE (best: 77.0us, R10):
//   extract_both8: both coord arrays -> u16 patterns; int4/thread, 4-lane
//     __shfl_xor nibble combine, 8 named in-flight loads (VGPR 32).
//   build_parts: 8 partitions x 64 slices, 32KB LDS hist, ds_add_f32 atomics.
//   reduce_parts: 64 slice-copies -> final 256KB hist.
//   gather_pat: out[i] = hist[pat_q[i]], ushort4/float4.
// Verdicts from the ladder: global fp32 atomics bypass L2 at ~19G ops/s (R0-2);
// LDS-partitioned build needs occupancy+ILP (R3->R4: 196->13us); extract is at
// ~6 TB/s achievable BW (R10); nt-hints (R12), DMA staging (R13) and
// cooperative fusion (R14: 569us, VGPR=12 register starvation) all fail to
// beat this. Remaining gap vs work-sum is launch overhead (~12us), proven
// unrecoverable.

#define REL_W 16
#define NBINS 65536
#define NPART 8
#define BPP 8192        // bins per partition (32 KB as floats)
#define NSLICES 64
#define BUILD_BLK 1024
#define BLK 256
#define EUNROLL 8       // int4s per thread in extract

typedef unsigned short ushort8_t __attribute__((ext_vector_type(8)));
typedef int int4v __attribute__((ext_vector_type(4)));

__device__ __forceinline__ unsigned pattern_of(const int* __restrict__ row) {
    const int4* p = reinterpret_cast<const int4*>(row);
    unsigned pat = 0;
#pragma unroll
    for (int k = 0; k < 4; ++k) {
        int4 v = p[k];
        pat |= (unsigned)(v.x & 1) << (k * 4 + 0);
        pat |= (unsigned)(v.y & 1) << (k * 4 + 1);
        pat |= (unsigned)(v.z & 1) << (k * 4 + 2);
        pat |= (unsigned)(v.w & 1) << (k * 4 + 3);
    }
    return pat;
}

__device__ __forceinline__ unsigned nibble_of(int4v v) {
    return (unsigned)(v.x & 1) | ((unsigned)(v.y & 1) << 1) |
           ((unsigned)(v.z & 1) << 2) | ((unsigned)(v.w & 1) << 3);
}

// combine 4-lane nibbles into a u16 pattern; lane k==0 of each group stores
__device__ __forceinline__ void emit_pat(unsigned g, unsigned nib, unsigned k, unsigned sh,
                                         unsigned short* __restrict__ dst) {
    unsigned val = nib << sh;
    val |= __shfl_xor(val, 1);
    val |= __shfl_xor(val, 2);
    if (k == 0) dst[g >> 2] = (unsigned short)val;
}

// 8 int4s per thread, spaced BLK apart (wave loads contiguous: 1KB/instr).
// Source select is block-uniform except the (at most one) boundary block.
__global__ __launch_bounds__(BLK) void extract_both8(const int* __restrict__ stored,
                                                     const int* __restrict__ queries,
                                                     unsigned short* __restrict__ pat_s,
                                                     unsigned short* __restrict__ pat_q,
                                                     int ns, int nq) {
    const int4v* sv = reinterpret_cast<const int4v*>(stored);
    const int4v* qv = reinterpret_cast<const int4v*>(queries);
    int ns4  = ns * 4;
    int tot4 = (ns + nq) * 4;
    int blk_lo = blockIdx.x * (BLK * EUNROLL);
    int blk_hi = blk_lo + BLK * EUNROLL;           // exclusive
    int base   = blk_lo + (int)threadIdx.x;
    unsigned k  = (unsigned)threadIdx.x & 3;       // group index (stride BLK keeps it)
    unsigned sh = 4 * k;

    if (blk_hi <= ns4) {
        // ---- pure stored block: 8 independent loads, then process ----
        int4v v0 = sv[base + 0 * BLK], v1 = sv[base + 1 * BLK];
        int4v v2 = sv[base + 2 * BLK], v3 = sv[base + 3 * BLK];
        int4v v4 = sv[base + 4 * BLK], v5 = sv[base + 5 * BLK];
        int4v v6 = sv[base + 6 * BLK], v7 = sv[base + 7 * BLK];
        emit_pat(base + 0 * BLK, nibble_of(v0), k, sh, pat_s);
        emit_pat(base + 1 * BLK, nibble_of(v1), k, sh, pat_s);
        emit_pat(base + 2 * BLK, nibble_of(v2), k, sh, pat_s);
        emit_pat(base + 3 * BLK, nibble_of(v3), k, sh, pat_s);
        emit_pat(base + 4 * BLK, nibble_of(v4), k, sh, pat_s);
        emit_pat(base + 5 * BLK, nibble_of(v5), k, sh, pat_s);
        emit_pat(base + 6 * BLK, nibble_of(v6), k, sh, pat_s);
        emit_pat(base + 7 * BLK, nibble_of(v7), k, sh, pat_s);
    } else if (blk_lo >= ns4 && blk_hi <= tot4) {
        // ---- pure query block ----
        int b = base - ns4;
        int4v v0 = qv[b + 0 * BLK], v1 = qv[b + 1 * BLK];
        int4v v2 = qv[b + 2 * BLK], v3 = qv[b + 3 * BLK];
        int4v v4 = qv[b + 4 * BLK], v5 = qv[b + 5 * BLK];
        int4v v6 = qv[b + 6 * BLK], v7 = qv[b + 7 * BLK];
        emit_pat(b + 0 * BLK, nibble_of(v0), k, sh, pat_q);
        emit_pat(b + 1 * BLK, nibble_of(v1), k, sh, pat_q);
        emit_pat(b + 2 * BLK, nibble_of(v2), k, sh, pat_q);
        emit_pat(b + 3 * BLK, nibble_of(v3), k, sh, pat_q);
        emit_pat(b + 4 * BLK, nibble_of(v4), k, sh, pat_q);
        emit_pat(b + 5 * BLK, nibble_of(v5), k, sh, pat_q);
        emit_pat(b + 6 * BLK, nibble_of(v6), k, sh, pat_q);
        emit_pat(b + 7 * BLK, nibble_of(v7), k, sh, pat_q);
    } else {
        // ---- boundary / tail block: per-element guarded path ----
#pragma unroll
        for (int j = 0; j < EUNROLL; ++j) {
            int g = base + j * BLK;
            if (g < tot4) {
                int4v v = (g < ns4) ? sv[g] : qv[g - ns4];
                unsigned val = nibble_of(v) << sh;
                val |= __shfl_xor(val, 1);
                val |= __shfl_xor(val, 2);
                if (k == 0) {
                    if (g < ns4) pat_s[g >> 2] = (unsigned short)val;
                    else         pat_q[(g - ns4) >> 2] = (unsigned short)val;
                }
            }
        }
    }
}

__global__ __launch_bounds__(BUILD_BLK) void build_parts(const unsigned short* __restrict__ pats,
                                                         const float* __restrict__ vals,
                                                         float* __restrict__ part_hists, int n) {
    __shared__ float lh[BPP];
    unsigned part  = blockIdx.x / NSLICES;
    unsigned slice = blockIdx.x % NSLICES;
    for (int b = threadIdx.x; b < BPP; b += BUILD_BLK) lh[b] = 0.0f;
    __syncthreads();

    int per = ((n + NSLICES - 1) / NSLICES + 7) & ~7;
    int lo = (int)slice * per;
    int hi = min(n, lo + per);
    if (lo < hi) {
        int m = hi - lo;
        int nvec = m >> 3;
        const ushort8_t* pv = reinterpret_cast<const ushort8_t*>(pats + lo);
        const float4*    vv = reinterpret_cast<const float4*>(vals + lo);
        for (int v = threadIdx.x; v < nvec; v += BUILD_BLK) {
            ushort8_t p8 = pv[v];
            float4 v0 = vv[2 * v];
            float4 v1 = vv[2 * v + 1];
            float vsc[8] = {v0.x, v0.y, v0.z, v0.w, v1.x, v1.y, v1.z, v1.w};
#pragma unroll
            for (int kk = 0; kk < 8; ++kk) {
                unsigned pat = p8[kk];
                if ((pat >> 13) == part)
                    atomicAdd(&lh[pat & (BPP - 1)], vsc[kk]);   // ds_add_f32, on-CU
            }
        }
        for (int i = lo + (nvec << 3) + (int)threadIdx.x; i < hi; i += BUILD_BLK) {
            unsigned pat = pats[i];
            if ((pat >> 13) == part)
                atomicAdd(&lh[pat & (BPP - 1)], vals[i]);
        }
    }
    __syncthreads();
    float* dst = part_hists + (size_t)blockIdx.x * BPP;
    for (int b = threadIdx.x; b < BPP; b += BUILD_BLK) dst[b] = lh[b];
}

__global__ void reduce_parts(const float* __restrict__ part_hists, float* __restrict__ final_h) {
    int g = blockIdx.x * blockDim.x + threadIdx.x;   // bin 0..65535
    unsigned part = (unsigned)g >> 13;
    unsigned b = (unsigned)g & (BPP - 1);
    const float* src = part_hists + ((size_t)part * NSLICES) * BPP + b;
    float s = 0.0f;
#pragma unroll 8
    for (int sl = 0; sl < NSLICES; ++sl) s += src[(size_t)sl * BPP];
    final_h[g] = s;
}

// tiny final gather: 4 queries per thread via ushort4 + float4 store
__global__ __launch_bounds__(BLK) void gather_pat(const unsigned short* __restrict__ pq,
                                                  const float* __restrict__ h,
                                                  float* __restrict__ out, int n) {
    int t = blockIdx.x * blockDim.x + threadIdx.x;
    int base = t * 4;
    if (base + 4 <= n) {
        ushort4 p4 = *reinterpret_cast<const ushort4*>(pq + base);
        float4 o;
        o.x = h[p4.x]; o.y = h[p4.y]; o.z = h[p4.z]; o.w = h[p4.w];
        *reinterpret_cast<float4*>(out + base) = o;
    } else {
        for (int i = base; i < n; ++i) out[i] = h[pq[i]];
    }
}

// ---- fallback (R0 path) if workspace too small ----
__global__ void build_hist_dev(const int* __restrict__ coords, const float* __restrict__ vals,
                               float* __restrict__ hist, int n) {
    int i = blockIdx.x * blockDim.x + threadIdx.x;
    if (i >= n) return;
    atomicAdd(&hist[pattern_of(coords + (size_t)i * REL_W)], vals[i]);
}
__global__ void gather_coord(const int* __restrict__ queries, const float* __restrict__ hist,
                             float* __restrict__ out, int n) {
    int i = blockIdx.x * blockDim.x + threadIdx.x;
    if (i >= n) return;
    out[i] = hist[pattern_of(queries + (size_t)i * REL_W)];
}

static inline size_t align_up(size_t x, size_t a) { return (x + a - 1) & ~(a - 1); }

extern "C" void kernel_launch(void* const* d_in, const int* in_sizes, int n_in,
                              void* d_out, int out_size, void* d_ws, size_t ws_size,
                              hipStream_t stream) {
    const int*   stored  = (const int*)d_in[0];   // [N_store, 16] int32
    const int*   queries = (const int*)d_in[1];   // [N_query, 16] int32
    const float* vals    = (const float*)d_in[2]; // [N_store] f32
    float*       out     = (float*)d_out;         // [N_query] f32

    int n_store = in_sizes[0] / REL_W;
    int n_query = in_sizes[1] / REL_W;

    // workspace layout
    size_t off_pat_s = 0;
    size_t off_pat_q = align_up(off_pat_s + (size_t)n_store * 2, 256);
    size_t off_hists = align_up(off_pat_q + (size_t)n_query * 2, 256);
    size_t off_final = off_hists + (size_t)NPART * NSLICES * BPP * sizeof(float);
    size_t need      = off_final + (size_t)NBINS * sizeof(float);

    if (ws_size >= need) {
        unsigned short* pat_s = (unsigned short*)((char*)d_ws + off_pat_s);
        unsigned short* pat_q = (unsigned short*)((char*)d_ws + off_pat_q);
        float* part_hists     = (float*)((char*)d_ws + off_hists);
        float* final_h        = (float*)((char*)d_ws + off_final);

        int tot4    = (n_store + n_query) * 4;
        int eblocks = (tot4 + BLK * EUNROLL - 1) / (BLK * EUNROLL);
        int gblocks = (n_query + BLK * 4 - 1) / (BLK * 4);
        extract_both8<<<eblocks, BLK, 0, stream>>>(stored, queries, pat_s, pat_q, n_store, n_query);
        build_parts<<<NPART * NSLICES, BUILD_BLK, 0, stream>>>(pat_s, vals, part_hists, n_store);
        reduce_parts<<<NBINS / BLK, BLK, 0, stream>>>(part_hists, final_h);
        gather_pat<<<gblocks, BLK, 0, stream>>>(pat_q, final_h, out, n_query);
    } else {
        float* hist = (float*)d_ws;
        hipMemsetAsync(d_ws, 0, NBINS * sizeof(float), stream);
        build_hist_dev<<<(n_store + BLK - 1) / BLK, BLK, 0, stream>>>(stored, vals, hist, n_store);
        gather_coord<<<(n_query + BLK - 1) / BLK, BLK, 0, stream>>>(queries, hist, out, n_query);
    }
}